// Round 7
// baseline (751.687 us; speedup 1.0000x reference)
//
#include <hip/hip_runtime.h>
#include <math.h>

#define NSTEPS 128
#define BATCH  32768
#define HID    64

constexpr float DTf = 1.0f / 128.0f;

struct CD { float c, dre, dim; };

// Literal transcription of one scan step's u-independent parts.
// Exact affine identity: u' = (1 - p*DT)*u + ef*delt0 (dN==0);
//                        u' = u + ef*dup/dum (dN = +1/-1).
__device__ __forceinline__ CD step_literal(
    float n, float x0, float x1, float x2, float p, float t,
    float db0, float db1, float db2, float dN, float phi,
    const float* __restrict__ w1, const float* __restrict__ b1,   // grad MLP (5,H),(H)
    const float* __restrict__ w2, const float* __restrict__ b2,   // (H,6),(6)
    const float* __restrict__ v1, const float* __restrict__ c1,   // jump MLP (5,H),(H)
    const float* __restrict__ v2, const float* __restrict__ c2)   // (H,2),(2)
{
    float og0=b2[0],og1=b2[1],og2=b2[2],og3=b2[3],og4=b2[4],og5=b2[5];
    for (int j = 0; j < HID; j++) {
        float z = n*w1[j] + x0*w1[HID+j] + x1*w1[2*HID+j] + x2*w1[3*HID+j]
                + p*w1[4*HID+j] + b1[j];
        float h = tanhf(z);
        const float* w2j = w2 + j*6;
        og0 += h*w2j[0]; og1 += h*w2j[1]; og2 += h*w2j[2];
        og3 += h*w2j[3]; og4 += h*w2j[4]; og5 += h*w2j[5];
    }
    float ui0=c2[0],  ui1=c2[1];
    float up0=c2[0],  up1=c2[1];
    float um0=c2[0],  um1=c2[1];
    for (int j = 0; j < HID; j++) {
        float d  = v1[j];
        float zb = n*d + x0*v1[HID+j] + x1*v1[2*HID+j] + x2*v1[3*HID+j]
                 + p*v1[4*HID+j] + c1[j];
        float h  = tanhf(zb);
        float hp = tanhf(zb + d);
        float hm = tanhf(zb - d);
        float w20 = v2[2*j], w21 = v2[2*j+1];
        ui0 += h *w20; ui1 += h *w21;
        up0 += hp*w20; up1 += hp*w21;
        um0 += hm*w20; um1 += hm*w21;
    }
    float dup0 = up0 - ui0, dup1 = up1 - ui1;
    float dum0 = um0 - ui0, dum1 = um1 - ui1;

    float x[3] = {x0, x1, x2};
    float S[3][3], Ti[3][3], M[3][3];
    float r2  = x0*x0 + x1*x1 + x2*x2;
    float inv = 1.0f / (1.0f + r2);
    for (int i = 0; i < 3; i++)
        for (int j2 = 0; j2 < 3; j2++) {
            S [i][j2] = (i==j2 ? 0.5f : 0.0f) + 0.1f*x[i]*x[j2];
            Ti[i][j2] = (i==j2 ? 1.0f : 0.0f) - x[i]*x[j2]*inv;
        }
    for (int i = 0; i < 3; i++)
        for (int k2 = 0; k2 < 3; k2++) {
            float s = 0.0f;
            for (int j2 = 0; j2 < 3; j2++) s += Ti[i][j2]*S[k2][j2];
            M[i][k2] = s;
        }
    float kc = sqrtf(2.0f*(0.5f + 0.1f*fabsf(n)));
    float gr[3] = {og0, og1, og2}, gi[3] = {og3, og4, og5};
    float db[3] = {db0, db1, db2};
    float gb_r = 0.0f, gb_i = 0.0f;
    for (int i = 0; i < 3; i++) {
        float mr = 0.0f;
        for (int j2 = 0; j2 < 3; j2++) mr += M[i][j2]*db[j2];
        gb_r += kc*gr[i]*mr;
        gb_i += kc*gi[i]*mr;
    }
    float alpha = 0.5f*(n + 1.0f);
    float beta  = 0.4f*fabsf(n) + 0.1f;
    float cf    = 0.1f*(1.0f + t)*DTf;
    float d0r = gb_r - (alpha*dup0 + beta*dum0)*DTf - cf*(og0+og1+og2);
    float d0i = gb_i - (alpha*dup1 + beta*dum1)*DTf - cf*(og3+og4+og5);

    float c, sr, si;
    if (dN > 0.5f)       { c = 1.0f;          sr = dup0; si = dup1; }
    else if (dN < -0.5f) { c = 1.0f;          sr = dum0; si = dum1; }
    else                 { c = 1.0f - p*DTf;  sr = d0r;  si = d0i;  }

    float sp = sinf(phi), cp = cosf(phi);
    CD o;
    o.c   = c;
    o.dre = cp*sr + sp*si;
    o.dim = cp*si - sp*sr;
    return o;
}

__device__ __forceinline__ void mlp_u0(
    float n, float x0, float x1, float x2, float p,
    const float* __restrict__ w1, const float* __restrict__ b1,
    const float* __restrict__ w2, const float* __restrict__ b2,
    float& ur, float& ui)
{
    float o0 = b2[0], o1 = b2[1];
    for (int j = 0; j < HID; j++) {
        float z = n*w1[j] + x0*w1[HID+j] + x1*w1[2*HID+j] + x2*w1[3*HID+j]
                + p*w1[4*HID+j] + b1[j];
        float h = tanhf(z);
        o0 += h*w2[2*j];
        o1 += h*w2[2*j+1];
    }
    ur = o0; ui = o1;
}

__global__ void __launch_bounds__(256) k_phi(
    const float* __restrict__ X, const float* __restrict__ P,
    float* __restrict__ phi, float* __restrict__ phiF)
{
    int b = blockIdx.x*256 + threadIdx.x;
    double s = 0.0;
    for (int k = 0; k < NSTEPS; k++) {
        size_t idx = (size_t)k*BATCH + b;
        phi[idx] = (float)(DTf * s);
        float p = P[idx];
        const float* xp = X + idx*3;
        float x0 = xp[0], x1 = xp[1], x2 = xp[2];
        s += (double)p * (double)(x0*x0 + x1*x1 + x2*x2);
    }
    phiF[b] = (float)(DTf * s);
}

__global__ void __launch_bounds__(256) k_step(
    const float* __restrict__ N,  const float* __restrict__ X,
    const float* __restrict__ P,  const float* __restrict__ Tarr,
    const float* __restrict__ dB,
    const float* __restrict__ Wg1, const float* __restrict__ bg1,
    const float* __restrict__ Wg2, const float* __restrict__ bg2,
    const float* __restrict__ Wj1, const float* __restrict__ bj1,
    const float* __restrict__ Wj2, const float* __restrict__ bj2,
    const float* __restrict__ phiA, float* __restrict__ cA, float2* __restrict__ dA)
{
    int k = blockIdx.y;
    int b = blockIdx.x*256 + threadIdx.x;
    size_t idx = (size_t)k*BATCH + b;
    float n = N[idx], p = P[idx], t = Tarr[k];
    const float* xp  = X  + idx*3;
    const float* dbp = dB + idx*3;
    float dN = N[idx + BATCH] - n;

    CD cd = step_literal(n, xp[0], xp[1], xp[2], p, t,
                         dbp[0], dbp[1], dbp[2], dN, phiA[idx],
                         Wg1 + k*5*HID, bg1 + k*HID, Wg2 + k*HID*6, bg2 + k*6,
                         Wj1 + k*5*HID, bj1 + k*HID, Wj2 + k*HID*2, bj2 + k*2);
    cA[idx] = cd.c;
    dA[idx] = make_float2(cd.dre, cd.dim);
}

// full=0 (out_size==2B): out = [re(u)(B); re(g)(B)]          (real-cast layout)
// full=1 (out_size==4B): out = [u_re; u_im; g_re; g_im]      (stacked pairs)
__global__ void __launch_bounds__(256) k_combine(
    const float* __restrict__ N, const float* __restrict__ X, const float* __restrict__ P,
    const float* __restrict__ Wr1, const float* __restrict__ br1,
    const float* __restrict__ Wr2, const float* __restrict__ br2,
    const float* __restrict__ cA, const float2* __restrict__ dA,
    const float* __restrict__ phiF, float* __restrict__ out, int full)
{
    int b = blockIdx.x*256 + threadIdx.x;
    const float* xp = X + (size_t)b*3;
    float ur, ui;
    mlp_u0(N[b], xp[0], xp[1], xp[2], P[b], Wr1, br1, Wr2, br2, ur, ui);
    for (int k = 0; k < NSTEPS; k++) {
        size_t idx = (size_t)k*BATCH + b;
        float  c = cA[idx];
        float2 d = dA[idx];
        ur = c*ur + d.x;
        ui = c*ui + d.y;
    }
    float phi = phiF[b];
    const float* xf = X + ((size_t)NSTEPS*BATCH + b)*3;
    float s = xf[0] + xf[1] + xf[2];
    float gre =  s*cosf(phi);
    float gim = -s*sinf(phi);
    if (full) {
        out[b]           = ur;
        out[BATCH + b]   = ui;
        out[2*BATCH + b] = gre;
        out[3*BATCH + b] = gim;
    } else {
        out[b]         = ur;
        out[BATCH + b] = gre;
    }
}

__global__ void __launch_bounds__(256) k_fused(
    const float* __restrict__ N,  const float* __restrict__ X,
    const float* __restrict__ P,  const float* __restrict__ Tarr,
    const float* __restrict__ dB,
    const float* __restrict__ Wr1, const float* __restrict__ br1,
    const float* __restrict__ Wr2, const float* __restrict__ br2,
    const float* __restrict__ Wg1, const float* __restrict__ bg1,
    const float* __restrict__ Wg2, const float* __restrict__ bg2,
    const float* __restrict__ Wj1, const float* __restrict__ bj1,
    const float* __restrict__ Wj2, const float* __restrict__ bj2,
    float* __restrict__ out, int full)
{
    int b = blockIdx.x*256 + threadIdx.x;
    float ur, ui;
    {
        const float* xp = X + (size_t)b*3;
        mlp_u0(N[b], xp[0], xp[1], xp[2], P[b], Wr1, br1, Wr2, br2, ur, ui);
    }
    double s = 0.0;
    for (int k = 0; k < NSTEPS; k++) {
        size_t idx = (size_t)k*BATCH + b;
        float n = N[idx], p = P[idx], t = Tarr[k];
        const float* xp  = X  + idx*3;
        const float* dbp = dB + idx*3;
        float dN  = N[idx + BATCH] - n;
        float phi = (float)(DTf * s);
        CD cd = step_literal(n, xp[0], xp[1], xp[2], p, t,
                             dbp[0], dbp[1], dbp[2], dN, phi,
                             Wg1 + k*5*HID, bg1 + k*HID, Wg2 + k*HID*6, bg2 + k*6,
                             Wj1 + k*5*HID, bj1 + k*HID, Wj2 + k*HID*2, bj2 + k*2);
        ur = cd.c*ur + cd.dre;
        ui = cd.c*ui + cd.dim;
        float x0 = xp[0], x1 = xp[1], x2 = xp[2];
        s += (double)p * (double)(x0*x0 + x1*x1 + x2*x2);
    }
    float phi = (float)(DTf * s);
    const float* xf = X + ((size_t)NSTEPS*BATCH + b)*3;
    float sm = xf[0] + xf[1] + xf[2];
    float gre =  sm*cosf(phi);
    float gim = -sm*sinf(phi);
    if (full) {
        out[b]           = ur;
        out[BATCH + b]   = ui;
        out[2*BATCH + b] = gre;
        out[3*BATCH + b] = gim;
    } else {
        out[b]         = ur;
        out[BATCH + b] = gre;
    }
}

extern "C" void kernel_launch(void* const* d_in, const int* in_sizes, int n_in,
                              void* d_out, int out_size, void* d_ws, size_t ws_size,
                              hipStream_t stream)
{
    const float* N    = (const float*)d_in[0];
    const float* X    = (const float*)d_in[1];
    const float* P    = (const float*)d_in[2];
    const float* Tarr = (const float*)d_in[3];
    const float* dB   = (const float*)d_in[4];
    const float* Wr1  = (const float*)d_in[5];
    const float* br1  = (const float*)d_in[6];
    const float* Wr2  = (const float*)d_in[7];
    const float* br2  = (const float*)d_in[8];
    const float* Wg1  = (const float*)d_in[9];
    const float* bg1  = (const float*)d_in[10];
    const float* Wg2  = (const float*)d_in[11];
    const float* bg2  = (const float*)d_in[12];
    const float* Wj1  = (const float*)d_in[13];
    const float* bj1  = (const float*)d_in[14];
    const float* Wj2  = (const float*)d_in[15];
    const float* bj2  = (const float*)d_in[16];
    float* out = (float*)d_out;

    // out_size == 2B  -> harness compares real parts only: [re(u); re(g)]
    // out_size == 4B  -> stacked real/imag pairs per output
    const int full = (out_size >= 4*BATCH) ? 1 : 0;

    const size_t phi_elems = (size_t)NSTEPS*BATCH;
    const size_t need = (phi_elems + BATCH + phi_elems)*sizeof(float)
                      + phi_elems*sizeof(float2);

    if (ws_size >= need) {
        float*  phiA = (float*)d_ws;
        float*  phiF = phiA + phi_elems;
        float*  cA   = phiF + BATCH;
        float2* dA   = (float2*)(cA + phi_elems);

        k_phi<<<dim3(BATCH/256), dim3(256), 0, stream>>>(X, P, phiA, phiF);
        k_step<<<dim3(BATCH/256, NSTEPS), dim3(256), 0, stream>>>(
            N, X, P, Tarr, dB, Wg1, bg1, Wg2, bg2, Wj1, bj1, Wj2, bj2,
            phiA, cA, dA);
        k_combine<<<dim3(BATCH/256), dim3(256), 0, stream>>>(
            N, X, P, Wr1, br1, Wr2, br2, cA, dA, phiF, out, full);
    } else {
        k_fused<<<dim3(BATCH/256), dim3(256), 0, stream>>>(
            N, X, P, Tarr, dB, Wr1, br1, Wr2, br2,
            Wg1, bg1, Wg2, bg2, Wj1, bj1, Wj2, bj2, out, full);
    }
}

// Round 8
// 320.339 us; speedup vs baseline: 2.3465x; 2.3465x over previous
//
#include <hip/hip_runtime.h>
#include <math.h>

#define NSTEPS 128
#define BATCH  32768
#define HID    64

constexpr float DTf = 1.0f / 128.0f;

struct CD { float c, dre, dim; };

// tanh(x) = 1 - 2/(exp(2x)+1) via hw exp2 + rcp. Saturates exactly to +-1.
__device__ __forceinline__ float fast_tanh(float x) {
    float e = __builtin_amdgcn_exp2f(x * 2.88539008177792681f); // 2*log2(e)
    return 1.0f - 2.0f * __builtin_amdgcn_rcpf(e + 1.0f);
}

// One scan step's u-independent affine coefficients:
//   u' = c*u + (dre + i*dim)
// c = 1-p*DT (dN==0) else 1;  d = ef * delt0  (ef = exp(-i*phi), |ef|=1).
// Jump MLP uses tanh addition identity: tanh(z+-d) = (T +- Td)/(1 +- T*Td),
// safe because |Td| = |tanh(Wj1_row0)| < 0.999 (rows ~ N(0,1/5)) -> 1-a^2 > 2e-3.
template<bool USE_TD>
__device__ __forceinline__ CD step_core(
    float n, float x0, float x1, float x2, float p, float t,
    float db0, float db1, float db2, float dN, float phi,
    const float* __restrict__ w1, const float* __restrict__ b1,   // grad MLP
    const float* __restrict__ w2, const float* __restrict__ b2,
    const float* __restrict__ v1, const float* __restrict__ c1,   // jump MLP
    const float* __restrict__ v2,
    const float* __restrict__ Td)                                  // tanh(v1 row0), LDS
{
    // ---- grad MLP: 5 -> 64 -> 6 (3 complex outputs) ----
    float og0=b2[0],og1=b2[1],og2=b2[2],og3=b2[3],og4=b2[4],og5=b2[5];
#pragma unroll 4
    for (int j = 0; j < HID; j++) {
        float z = fmaf(n, w1[j],
                  fmaf(x0, w1[HID+j],
                  fmaf(x1, w1[2*HID+j],
                  fmaf(x2, w1[3*HID+j],
                  fmaf(p,  w1[4*HID+j], b1[j])))));
        float h = fast_tanh(z);
        const float* w2j = w2 + j*6;
        og0 = fmaf(h, w2j[0], og0); og1 = fmaf(h, w2j[1], og1); og2 = fmaf(h, w2j[2], og2);
        og3 = fmaf(h, w2j[3], og3); og4 = fmaf(h, w2j[4], og4); og5 = fmaf(h, w2j[5], og5);
    }
    // ---- jump MLP: dup/dum via tanh addition identity (biases of W2 cancel) ----
    float dup0=0.f, dup1=0.f, dum0=0.f, dum1=0.f;
#pragma unroll 4
    for (int j = 0; j < HID; j++) {
        float d  = v1[j];                       // Wj1[k][0][j] (n-feature row)
        float zb = fmaf(n, d,
                   fmaf(x0, v1[HID+j],
                   fmaf(x1, v1[2*HID+j],
                   fmaf(x2, v1[3*HID+j],
                   fmaf(p,  v1[4*HID+j], c1[j])))));
        float T   = fast_tanh(zb);
        float Tdv = USE_TD ? Td[j] : fast_tanh(d);
        float a   = T * Tdv;
        float r   = __builtin_amdgcn_rcpf(fmaf(-a, a, 1.0f));  // 1/(1-a^2)
        float ep  = (T + Tdv) * (1.0f - a) * r - T;            // tanh(zb+d) - tanh(zb)
        float em  = (T - Tdv) * (1.0f + a) * r - T;            // tanh(zb-d) - tanh(zb)
        float w20 = v2[2*j], w21 = v2[2*j+1];
        dup0 = fmaf(ep, w20, dup0); dup1 = fmaf(ep, w21, dup1);
        dum0 = fmaf(em, w20, dum0); dum1 = fmaf(em, w21, dum1);
    }
    // ---- M = Ti@S^T = 0.5 I + gamma x x^T ;  grad_bmm = kc * g.(M db) ----
    float r2    = fmaf(x0,x0, fmaf(x1,x1, x2*x2));
    float gamma = 0.1f - (0.5f + 0.1f*r2) * __builtin_amdgcn_rcpf(1.0f + r2);
    float xdb   = fmaf(x0,db0, fmaf(x1,db1, x2*db2));
    float kc    = sqrtf(fmaf(0.2f, fabsf(n), 1.0f));           // sqrt(2*D(n))
    float gdb_r = fmaf(og0,db0, fmaf(og1,db1, og2*db2));
    float gdb_i = fmaf(og3,db0, fmaf(og4,db1, og5*db2));
    float gx_r  = fmaf(og0,x0,  fmaf(og1,x1,  og2*x2));
    float gx_i  = fmaf(og3,x0,  fmaf(og4,x1,  og5*x2));
    float gb_r  = kc * fmaf(gamma*xdb, gx_r, 0.5f*gdb_r);
    float gb_i  = kc * fmaf(gamma*xdb, gx_i, 0.5f*gdb_i);

    float alpha = 0.5f*(n + 1.0f);
    float beta  = fmaf(0.4f, fabsf(n), 0.1f);
    float cf    = 0.1f*(1.0f + t)*DTf;
    float d0r = gb_r - (alpha*dup0 + beta*dum0)*DTf - cf*(og0+og1+og2);
    float d0i = gb_i - (alpha*dup1 + beta*dum1)*DTf - cf*(og3+og4+og5);

    float c, sr, si;
    if (dN > 0.5f)       { c = 1.0f;          sr = dup0; si = dup1; }
    else if (dN < -0.5f) { c = 1.0f;          sr = dum0; si = dum1; }
    else                 { c = 1.0f - p*DTf;  sr = d0r;  si = d0i;  }

    // d = exp(-i*phi) * (sr + i*si)
    float sp, cp;
    __sincosf(phi, &sp, &cp);
    CD o;
    o.c   = c;
    o.dre = fmaf(cp, sr,  sp*si);
    o.dim = fmaf(cp, si, -sp*sr);
    return o;
}

__device__ __forceinline__ void mlp_u0(
    float n, float x0, float x1, float x2, float p,
    const float* __restrict__ w1, const float* __restrict__ b1,
    const float* __restrict__ w2, const float* __restrict__ b2,
    float& ur, float& ui)
{
    float o0 = b2[0], o1 = b2[1];
#pragma unroll 4
    for (int j = 0; j < HID; j++) {
        float z = fmaf(n, w1[j],
                  fmaf(x0, w1[HID+j],
                  fmaf(x1, w1[2*HID+j],
                  fmaf(x2, w1[3*HID+j],
                  fmaf(p,  w1[4*HID+j], b1[j])))));
        float h = fast_tanh(z);
        o0 = fmaf(h, w2[2*j],   o0);
        o1 = fmaf(h, w2[2*j+1], o1);
    }
    ur = o0; ui = o1;
}

// ---- Pass 1: phi_k = DT * sum_{j<k} p_j*|x_j|^2 (double accumulator) ----
__global__ void __launch_bounds__(256) k_phi(
    const float* __restrict__ X, const float* __restrict__ P,
    float* __restrict__ phi, float* __restrict__ phiF)
{
    int b = blockIdx.x*256 + threadIdx.x;
    double s = 0.0;
    for (int k = 0; k < NSTEPS; k++) {
        size_t idx = (size_t)k*BATCH + b;
        phi[idx] = (float)(DTf * s);
        float p = P[idx];
        const float* xp = X + idx*3;
        float x0 = xp[0], x1 = xp[1], x2 = xp[2];
        s += (double)p * (double)(x0*x0 + x1*x1 + x2*x2);
    }
    phiF[b] = (float)(DTf * s);
}

// ---- Pass 2: per-(step,path) affine coefficients; fully parallel ----
__global__ void __launch_bounds__(256) k_step(
    const float* __restrict__ N,  const float* __restrict__ X,
    const float* __restrict__ P,  const float* __restrict__ Tarr,
    const float* __restrict__ dB,
    const float* __restrict__ Wg1, const float* __restrict__ bg1,
    const float* __restrict__ Wg2, const float* __restrict__ bg2,
    const float* __restrict__ Wj1, const float* __restrict__ bj1,
    const float* __restrict__ Wj2, const float* __restrict__ bj2,
    const float* __restrict__ phiA, float* __restrict__ cA, float2* __restrict__ dA)
{
    int k = blockIdx.y;                         // wave-uniform -> scalar weight loads
    const float* w1 = Wg1 + k*5*HID;
    const float* b1 = bg1 + k*HID;
    const float* w2 = Wg2 + k*HID*6;
    const float* b2 = bg2 + k*6;
    const float* v1 = Wj1 + k*5*HID;
    const float* c1 = bj1 + k*HID;
    const float* v2 = Wj2 + k*HID*2;

    __shared__ float Td[HID];
    if (threadIdx.x < HID) Td[threadIdx.x] = fast_tanh(v1[threadIdx.x]);
    __syncthreads();

    int b = blockIdx.x*256 + threadIdx.x;
    size_t idx = (size_t)k*BATCH + b;
    float n = N[idx], p = P[idx], t = Tarr[k];
    const float* xp  = X  + idx*3;
    const float* dbp = dB + idx*3;
    float dN  = N[idx + BATCH] - n;             // exact in fp32
    float phi = phiA[idx];

    CD cd = step_core<true>(n, xp[0], xp[1], xp[2], p, t,
                            dbp[0], dbp[1], dbp[2], dN, phi,
                            w1, b1, w2, b2, v1, c1, v2, Td);
    cA[idx] = cd.c;
    dA[idx] = make_float2(cd.dre, cd.dim);
}

// ---- Pass 3: u0 MLP + 128-term affine fold + g ----
// full=0 (out_size==2B): out = [re(u)(B); re(g)(B)]
// full=1 (out_size==4B): out = [u_re; u_im; g_re; g_im]
__global__ void __launch_bounds__(256) k_combine(
    const float* __restrict__ N, const float* __restrict__ X, const float* __restrict__ P,
    const float* __restrict__ Wr1, const float* __restrict__ br1,
    const float* __restrict__ Wr2, const float* __restrict__ br2,
    const float* __restrict__ cA, const float2* __restrict__ dA,
    const float* __restrict__ phiF, float* __restrict__ out, int full)
{
    int b = blockIdx.x*256 + threadIdx.x;
    const float* xp = X + (size_t)b*3;
    float ur, ui;
    mlp_u0(N[b], xp[0], xp[1], xp[2], P[b], Wr1, br1, Wr2, br2, ur, ui);
#pragma unroll 8
    for (int k = 0; k < NSTEPS; k++) {
        size_t idx = (size_t)k*BATCH + b;
        float  c = cA[idx];
        float2 d = dA[idx];
        ur = fmaf(c, ur, d.x);
        ui = fmaf(c, ui, d.y);
    }
    float phi = phiF[b];
    const float* xf = X + ((size_t)NSTEPS*BATCH + b)*3;
    float s = xf[0] + xf[1] + xf[2];
    float sp, cp;
    __sincosf(phi, &sp, &cp);
    float gre =  s*cp;
    float gim = -s*sp;
    if (full) {
        out[b]           = ur;
        out[BATCH + b]   = ui;
        out[2*BATCH + b] = gre;
        out[3*BATCH + b] = gim;
    } else {
        out[b]         = ur;
        out[BATCH + b] = gre;
    }
}

// ---- Fallback (no workspace): fully fused sequential scan per path ----
__global__ void __launch_bounds__(256) k_fused(
    const float* __restrict__ N,  const float* __restrict__ X,
    const float* __restrict__ P,  const float* __restrict__ Tarr,
    const float* __restrict__ dB,
    const float* __restrict__ Wr1, const float* __restrict__ br1,
    const float* __restrict__ Wr2, const float* __restrict__ br2,
    const float* __restrict__ Wg1, const float* __restrict__ bg1,
    const float* __restrict__ Wg2, const float* __restrict__ bg2,
    const float* __restrict__ Wj1, const float* __restrict__ bj1,
    const float* __restrict__ Wj2, const float* __restrict__ bj2,
    float* __restrict__ out, int full)
{
    int b = blockIdx.x*256 + threadIdx.x;
    float ur, ui;
    {
        const float* xp = X + (size_t)b*3;
        mlp_u0(N[b], xp[0], xp[1], xp[2], P[b], Wr1, br1, Wr2, br2, ur, ui);
    }
    double s = 0.0;
    for (int k = 0; k < NSTEPS; k++) {
        size_t idx = (size_t)k*BATCH + b;
        float n = N[idx], p = P[idx], t = Tarr[k];
        const float* xp  = X  + idx*3;
        const float* dbp = dB + idx*3;
        float dN  = N[idx + BATCH] - n;
        float phi = (float)(DTf * s);
        CD cd = step_core<false>(n, xp[0], xp[1], xp[2], p, t,
                                 dbp[0], dbp[1], dbp[2], dN, phi,
                                 Wg1 + k*5*HID, bg1 + k*HID,
                                 Wg2 + k*HID*6, bg2 + k*6,
                                 Wj1 + k*5*HID, bj1 + k*HID,
                                 Wj2 + k*HID*2, nullptr);
        ur = fmaf(cd.c, ur, cd.dre);
        ui = fmaf(cd.c, ui, cd.dim);
        float x0 = xp[0], x1 = xp[1], x2 = xp[2];
        s += (double)p * (double)(x0*x0 + x1*x1 + x2*x2);
    }
    float phi = (float)(DTf * s);
    const float* xf = X + ((size_t)NSTEPS*BATCH + b)*3;
    float sm = xf[0] + xf[1] + xf[2];
    float sp, cp;
    __sincosf(phi, &sp, &cp);
    float gre =  sm*cp;
    float gim = -sm*sp;
    if (full) {
        out[b]           = ur;
        out[BATCH + b]   = ui;
        out[2*BATCH + b] = gre;
        out[3*BATCH + b] = gim;
    } else {
        out[b]         = ur;
        out[BATCH + b] = gre;
    }
}

extern "C" void kernel_launch(void* const* d_in, const int* in_sizes, int n_in,
                              void* d_out, int out_size, void* d_ws, size_t ws_size,
                              hipStream_t stream)
{
    const float* N    = (const float*)d_in[0];
    const float* X    = (const float*)d_in[1];
    const float* P    = (const float*)d_in[2];
    const float* Tarr = (const float*)d_in[3];
    const float* dB   = (const float*)d_in[4];
    const float* Wr1  = (const float*)d_in[5];
    const float* br1  = (const float*)d_in[6];
    const float* Wr2  = (const float*)d_in[7];
    const float* br2  = (const float*)d_in[8];
    const float* Wg1  = (const float*)d_in[9];
    const float* bg1  = (const float*)d_in[10];
    const float* Wg2  = (const float*)d_in[11];
    const float* bg2  = (const float*)d_in[12];
    const float* Wj1  = (const float*)d_in[13];
    const float* bj1  = (const float*)d_in[14];
    const float* Wj2  = (const float*)d_in[15];
    const float* bj2  = (const float*)d_in[16];
    float* out = (float*)d_out;

    const int full = (out_size >= 4*BATCH) ? 1 : 0;

    const size_t phi_elems = (size_t)NSTEPS*BATCH;
    const size_t need = (phi_elems + BATCH + phi_elems)*sizeof(float)
                      + phi_elems*sizeof(float2);

    if (ws_size >= need) {
        float*  phiA = (float*)d_ws;
        float*  phiF = phiA + phi_elems;
        float*  cA   = phiF + BATCH;
        float2* dA   = (float2*)(cA + phi_elems);

        k_phi<<<dim3(BATCH/256), dim3(256), 0, stream>>>(X, P, phiA, phiF);
        k_step<<<dim3(BATCH/256, NSTEPS), dim3(256), 0, stream>>>(
            N, X, P, Tarr, dB, Wg1, bg1, Wg2, bg2, Wj1, bj1, Wj2, bj2,
            phiA, cA, dA);
        k_combine<<<dim3(BATCH/256), dim3(256), 0, stream>>>(
            N, X, P, Wr1, br1, Wr2, br2, cA, dA, phiF, out, full);
    } else {
        k_fused<<<dim3(BATCH/256), dim3(256), 0, stream>>>(
            N, X, P, Tarr, dB, Wr1, br1, Wr2, br2,
            Wg1, bg1, Wg2, bg2, Wj1, bj1, Wj2, bj2, out, full);
    }
}

// Round 9
// 280.007 us; speedup vs baseline: 2.6845x; 1.1440x over previous
//
#include <hip/hip_runtime.h>
#include <math.h>

#define NSTEPS 128
#define BATCH  32768
#define HID    64

constexpr float DTf = 1.0f / 128.0f;
constexpr float TWO_LOG2E = 2.88539008177792681f;

typedef float v2f __attribute__((ext_vector_type(2)));

__device__ __forceinline__ v2f v2ld(const float* p) { return *(const v2f*)p; }

struct CD { float c, dre, dim; };

// scalar tanh via hw exp2 + rcp (saturates exactly)
__device__ __forceinline__ float fast_tanh(float x) {
    float e = __builtin_amdgcn_exp2f(x * TWO_LOG2E);
    return 1.0f - 2.0f * __builtin_amdgcn_rcpf(e + 1.0f);
}
// packed-pair tanh: VALU parts pack to v_pk_*, exp2/rcp per-component (trans)
__device__ __forceinline__ v2f fast_tanh2(v2f z) {
    v2f zs = z * TWO_LOG2E;                         // pk_mul
    v2f e;
    e.x = __builtin_amdgcn_exp2f(zs.x);
    e.y = __builtin_amdgcn_exp2f(zs.y);
    v2f e1 = e + 1.0f;                              // pk_add
    v2f r;
    r.x = __builtin_amdgcn_rcpf(e1.x);
    r.y = __builtin_amdgcn_rcpf(e1.y);
    return 1.0f - 2.0f * r;                         // pk ops
}

// One scan step's u-independent affine coefficients: u' = c*u + (dre + i*dim).
// Jump MLP via tanh addition identity (safe: |Td|<0.999 -> 1-a^2 > 2e-3).
// All inner-loop math packed 2-wide (hidden units j, j+1) -> v_pk_fma_f32.
template<bool USE_TD>
__device__ __forceinline__ CD step_core(
    float n, float x0, float x1, float x2, float p, float t,
    float db0, float db1, float db2, float dN, float phi,
    const float* __restrict__ w1, const float* __restrict__ b1,   // grad MLP
    const float* __restrict__ w2, const float* __restrict__ b2,
    const float* __restrict__ v1, const float* __restrict__ c1,   // jump MLP
    const float* __restrict__ vw2,
    const float* __restrict__ Td)                                  // tanh(v1 row0), LDS
{
    // ---- grad MLP: 5 -> 64 -> 6, packed pairs ----
    v2f og01 = { b2[0], b2[1] };
    v2f og23 = { b2[2], b2[3] };
    v2f og45 = { b2[4], b2[5] };
#pragma unroll 4
    for (int j = 0; j < HID; j += 2) {
        v2f z = n  * v2ld(w1 + j)
              + x0 * v2ld(w1 + HID   + j)
              + x1 * v2ld(w1 + 2*HID + j)
              + x2 * v2ld(w1 + 3*HID + j)
              + p  * v2ld(w1 + 4*HID + j)
              + v2ld(b1 + j);
        v2f h = fast_tanh2(z);
        const float* wj = w2 + j*6;                 // rows j and j+1 contiguous
        og01 += h.x * v2ld(wj)     + h.y * v2ld(wj + 6);
        og23 += h.x * v2ld(wj + 2) + h.y * v2ld(wj + 8);
        og45 += h.x * v2ld(wj + 4) + h.y * v2ld(wj + 10);
    }
    float og0 = og01.x, og1 = og01.y, og2 = og23.x;
    float og3 = og23.y, og4 = og45.x, og5 = og45.y;

    // ---- jump MLP: dup/dum via addition identity, packed pairs ----
    v2f dup01 = { 0.f, 0.f };
    v2f dum01 = { 0.f, 0.f };
#pragma unroll 4
    for (int j = 0; j < HID; j += 2) {
        v2f d  = v2ld(v1 + j);                      // Wj1 row0 (n-feature)
        v2f zb = n  * d
               + x0 * v2ld(v1 + HID   + j)
               + x1 * v2ld(v1 + 2*HID + j)
               + x2 * v2ld(v1 + 3*HID + j)
               + p  * v2ld(v1 + 4*HID + j)
               + v2ld(c1 + j);
        v2f T  = fast_tanh2(zb);
        v2f Tv;
        if (USE_TD) Tv = v2ld(Td + j);
        else { Tv.x = fast_tanh(d.x); Tv.y = fast_tanh(d.y); }
        v2f a    = T * Tv;
        v2f oma2 = 1.0f - a*a;                      // pk_fma
        v2f r;
        r.x = __builtin_amdgcn_rcpf(oma2.x);
        r.y = __builtin_amdgcn_rcpf(oma2.y);
        v2f ep = (T + Tv) * (1.0f - a) * r - T;     // tanh(zb+d)-tanh(zb)
        v2f em = (T - Tv) * (1.0f + a) * r - T;     // tanh(zb-d)-tanh(zb)
        v2f wv0 = v2ld(vw2 + 2*j);                  // Wj2 rows j, j+1 (2 floats each)
        v2f wv1 = v2ld(vw2 + 2*j + 2);
        dup01 += ep.x * wv0 + ep.y * wv1;
        dum01 += em.x * wv0 + em.y * wv1;
    }
    float dup0 = dup01.x, dup1 = dup01.y;
    float dum0 = dum01.x, dum1 = dum01.y;

    // ---- M = Ti@S^T = 0.5 I + gamma x x^T ;  grad_bmm = kc * g.(M db) ----
    float r2    = fmaf(x0,x0, fmaf(x1,x1, x2*x2));
    float gamma = 0.1f - (0.5f + 0.1f*r2) * __builtin_amdgcn_rcpf(1.0f + r2);
    float xdb   = fmaf(x0,db0, fmaf(x1,db1, x2*db2));
    float kc    = sqrtf(fmaf(0.2f, fabsf(n), 1.0f));           // sqrt(2*D(n))
    float gdb_r = fmaf(og0,db0, fmaf(og1,db1, og2*db2));
    float gdb_i = fmaf(og3,db0, fmaf(og4,db1, og5*db2));
    float gx_r  = fmaf(og0,x0,  fmaf(og1,x1,  og2*x2));
    float gx_i  = fmaf(og3,x0,  fmaf(og4,x1,  og5*x2));
    float gb_r  = kc * fmaf(gamma*xdb, gx_r, 0.5f*gdb_r);
    float gb_i  = kc * fmaf(gamma*xdb, gx_i, 0.5f*gdb_i);

    float alpha = 0.5f*(n + 1.0f);
    float beta  = fmaf(0.4f, fabsf(n), 0.1f);
    float cf    = 0.1f*(1.0f + t)*DTf;
    float d0r = gb_r - (alpha*dup0 + beta*dum0)*DTf - cf*(og0+og1+og2);
    float d0i = gb_i - (alpha*dup1 + beta*dum1)*DTf - cf*(og3+og4+og5);

    float c, sr, si;
    if (dN > 0.5f)       { c = 1.0f;          sr = dup0; si = dup1; }
    else if (dN < -0.5f) { c = 1.0f;          sr = dum0; si = dum1; }
    else                 { c = 1.0f - p*DTf;  sr = d0r;  si = d0i;  }

    float sp, cp;
    __sincosf(phi, &sp, &cp);
    CD o;
    o.c   = c;
    o.dre = fmaf(cp, sr,  sp*si);
    o.dim = fmaf(cp, si, -sp*sr);
    return o;
}

__device__ __forceinline__ void mlp_u0(
    float n, float x0, float x1, float x2, float p,
    const float* __restrict__ w1, const float* __restrict__ b1,
    const float* __restrict__ w2, const float* __restrict__ b2,
    float& ur, float& ui)
{
    v2f o01 = { b2[0], b2[1] };
#pragma unroll 4
    for (int j = 0; j < HID; j += 2) {
        v2f z = n  * v2ld(w1 + j)
              + x0 * v2ld(w1 + HID   + j)
              + x1 * v2ld(w1 + 2*HID + j)
              + x2 * v2ld(w1 + 3*HID + j)
              + p  * v2ld(w1 + 4*HID + j)
              + v2ld(b1 + j);
        v2f h = fast_tanh2(z);
        o01 += h.x * v2ld(w2 + 2*j) + h.y * v2ld(w2 + 2*j + 2);
    }
    ur = o01.x; ui = o01.y;
}

// ---- Pass 1: phi_k = DT * sum_{j<k} p_j*|x_j|^2 ----
__global__ void __launch_bounds__(256) k_phi(
    const float* __restrict__ X, const float* __restrict__ P,
    float* __restrict__ phi, float* __restrict__ phiF)
{
    int b = blockIdx.x*256 + threadIdx.x;
    double s = 0.0;
    for (int k = 0; k < NSTEPS; k++) {
        size_t idx = (size_t)k*BATCH + b;
        phi[idx] = (float)(DTf * s);
        float p = P[idx];
        const float* xp = X + idx*3;
        float x0 = xp[0], x1 = xp[1], x2 = xp[2];
        s += (double)p * (double)(x0*x0 + x1*x1 + x2*x2);
    }
    phiF[b] = (float)(DTf * s);
}

// ---- Pass 2: per-(step,path) affine coefficients ----
__global__ void __launch_bounds__(256) k_step(
    const float* __restrict__ N,  const float* __restrict__ X,
    const float* __restrict__ P,  const float* __restrict__ Tarr,
    const float* __restrict__ dB,
    const float* __restrict__ Wg1, const float* __restrict__ bg1,
    const float* __restrict__ Wg2, const float* __restrict__ bg2,
    const float* __restrict__ Wj1, const float* __restrict__ bj1,
    const float* __restrict__ Wj2, const float* __restrict__ bj2,
    const float* __restrict__ phiA, float* __restrict__ cA, float2* __restrict__ dA)
{
    int k = blockIdx.y;                         // wave-uniform
    const float* w1 = Wg1 + k*5*HID;
    const float* b1 = bg1 + k*HID;
    const float* w2 = Wg2 + k*HID*6;
    const float* b2 = bg2 + k*6;
    const float* v1 = Wj1 + k*5*HID;
    const float* c1 = bj1 + k*HID;
    const float* vw2 = Wj2 + k*HID*2;

    __shared__ float Td[HID];
    if (threadIdx.x < HID) Td[threadIdx.x] = fast_tanh(v1[threadIdx.x]);
    __syncthreads();

    int b = blockIdx.x*256 + threadIdx.x;
    size_t idx = (size_t)k*BATCH + b;
    float n = N[idx], p = P[idx], t = Tarr[k];
    const float* xp  = X  + idx*3;
    const float* dbp = dB + idx*3;
    float dN  = N[idx + BATCH] - n;
    float phi = phiA[idx];

    CD cd = step_core<true>(n, xp[0], xp[1], xp[2], p, t,
                            dbp[0], dbp[1], dbp[2], dN, phi,
                            w1, b1, w2, b2, v1, c1, vw2, Td);
    cA[idx] = cd.c;
    dA[idx] = make_float2(cd.dre, cd.dim);
}

// ---- Pass 3: u0 MLP + affine fold + g ----
// full=0: out = [re(u); re(g)] ; full=1: out = [u_re; u_im; g_re; g_im]
__global__ void __launch_bounds__(256) k_combine(
    const float* __restrict__ N, const float* __restrict__ X, const float* __restrict__ P,
    const float* __restrict__ Wr1, const float* __restrict__ br1,
    const float* __restrict__ Wr2, const float* __restrict__ br2,
    const float* __restrict__ cA, const float2* __restrict__ dA,
    const float* __restrict__ phiF, float* __restrict__ out, int full)
{
    int b = blockIdx.x*256 + threadIdx.x;
    const float* xp = X + (size_t)b*3;
    float ur, ui;
    mlp_u0(N[b], xp[0], xp[1], xp[2], P[b], Wr1, br1, Wr2, br2, ur, ui);
#pragma unroll 8
    for (int k = 0; k < NSTEPS; k++) {
        size_t idx = (size_t)k*BATCH + b;
        float  c = cA[idx];
        float2 d = dA[idx];
        ur = fmaf(c, ur, d.x);
        ui = fmaf(c, ui, d.y);
    }
    float phi = phiF[b];
    const float* xf = X + ((size_t)NSTEPS*BATCH + b)*3;
    float s = xf[0] + xf[1] + xf[2];
    float sp, cp;
    __sincosf(phi, &sp, &cp);
    float gre =  s*cp;
    float gim = -s*sp;
    if (full) {
        out[b]           = ur;
        out[BATCH + b]   = ui;
        out[2*BATCH + b] = gre;
        out[3*BATCH + b] = gim;
    } else {
        out[b]         = ur;
        out[BATCH + b] = gre;
    }
}

// ---- Fallback (no workspace): fused sequential scan ----
__global__ void __launch_bounds__(256) k_fused(
    const float* __restrict__ N,  const float* __restrict__ X,
    const float* __restrict__ P,  const float* __restrict__ Tarr,
    const float* __restrict__ dB,
    const float* __restrict__ Wr1, const float* __restrict__ br1,
    const float* __restrict__ Wr2, const float* __restrict__ br2,
    const float* __restrict__ Wg1, const float* __restrict__ bg1,
    const float* __restrict__ Wg2, const float* __restrict__ bg2,
    const float* __restrict__ Wj1, const float* __restrict__ bj1,
    const float* __restrict__ Wj2, const float* __restrict__ bj2,
    float* __restrict__ out, int full)
{
    int b = blockIdx.x*256 + threadIdx.x;
    float ur, ui;
    {
        const float* xp = X + (size_t)b*3;
        mlp_u0(N[b], xp[0], xp[1], xp[2], P[b], Wr1, br1, Wr2, br2, ur, ui);
    }
    double s = 0.0;
    for (int k = 0; k < NSTEPS; k++) {
        size_t idx = (size_t)k*BATCH + b;
        float n = N[idx], p = P[idx], t = Tarr[k];
        const float* xp  = X  + idx*3;
        const float* dbp = dB + idx*3;
        float dN  = N[idx + BATCH] - n;
        float phi = (float)(DTf * s);
        CD cd = step_core<false>(n, xp[0], xp[1], xp[2], p, t,
                                 dbp[0], dbp[1], dbp[2], dN, phi,
                                 Wg1 + k*5*HID, bg1 + k*HID,
                                 Wg2 + k*HID*6, bg2 + k*6,
                                 Wj1 + k*5*HID, bj1 + k*HID,
                                 Wj2 + k*HID*2, nullptr);
        ur = fmaf(cd.c, ur, cd.dre);
        ui = fmaf(cd.c, ui, cd.dim);
        float x0 = xp[0], x1 = xp[1], x2 = xp[2];
        s += (double)p * (double)(x0*x0 + x1*x1 + x2*x2);
    }
    float phi = (float)(DTf * s);
    const float* xf = X + ((size_t)NSTEPS*BATCH + b)*3;
    float sm = xf[0] + xf[1] + xf[2];
    float sp, cp;
    __sincosf(phi, &sp, &cp);
    float gre =  sm*cp;
    float gim = -sm*sp;
    if (full) {
        out[b]           = ur;
        out[BATCH + b]   = ui;
        out[2*BATCH + b] = gre;
        out[3*BATCH + b] = gim;
    } else {
        out[b]         = ur;
        out[BATCH + b] = gre;
    }
}

extern "C" void kernel_launch(void* const* d_in, const int* in_sizes, int n_in,
                              void* d_out, int out_size, void* d_ws, size_t ws_size,
                              hipStream_t stream)
{
    const float* N    = (const float*)d_in[0];
    const float* X    = (const float*)d_in[1];
    const float* P    = (const float*)d_in[2];
    const float* Tarr = (const float*)d_in[3];
    const float* dB   = (const float*)d_in[4];
    const float* Wr1  = (const float*)d_in[5];
    const float* br1  = (const float*)d_in[6];
    const float* Wr2  = (const float*)d_in[7];
    const float* br2  = (const float*)d_in[8];
    const float* Wg1  = (const float*)d_in[9];
    const float* bg1  = (const float*)d_in[10];
    const float* Wg2  = (const float*)d_in[11];
    const float* bg2  = (const float*)d_in[12];
    const float* Wj1  = (const float*)d_in[13];
    const float* bj1  = (const float*)d_in[14];
    const float* Wj2  = (const float*)d_in[15];
    const float* bj2  = (const float*)d_in[16];
    float* out = (float*)d_out;

    const int full = (out_size >= 4*BATCH) ? 1 : 0;

    const size_t phi_elems = (size_t)NSTEPS*BATCH;
    const size_t need = (phi_elems + BATCH + phi_elems)*sizeof(float)
                      + phi_elems*sizeof(float2);

    if (ws_size >= need) {
        float*  phiA = (float*)d_ws;
        float*  phiF = phiA + phi_elems;
        float*  cA   = phiF + BATCH;
        float2* dA   = (float2*)(cA + phi_elems);

        k_phi<<<dim3(BATCH/256), dim3(256), 0, stream>>>(X, P, phiA, phiF);
        k_step<<<dim3(BATCH/256, NSTEPS), dim3(256), 0, stream>>>(
            N, X, P, Tarr, dB, Wg1, bg1, Wg2, bg2, Wj1, bj1, Wj2, bj2,
            phiA, cA, dA);
        k_combine<<<dim3(BATCH/256), dim3(256), 0, stream>>>(
            N, X, P, Wr1, br1, Wr2, br2, cA, dA, phiF, out, full);
    } else {
        k_fused<<<dim3(BATCH/256), dim3(256), 0, stream>>>(
            N, X, P, Tarr, dB, Wr1, br1, Wr2, br2,
            Wg1, bg1, Wg2, bg2, Wj1, bj1, Wj2, bj2, out, full);
    }
}